// Round 1
// baseline (3246.561 us; speedup 1.0000x reference)
//
#include <hip/hip_runtime.h>
#include <math.h>

#define NNODES 20000
#define NEDGES 320000

// ---------------------------------------------------------------- h0 = x * node_imp
__global__ __launch_bounds__(256) void k_premul(const float* __restrict__ x,
                                                const float* __restrict__ ni,
                                                float* __restrict__ h, int n4) {
    int i = blockIdx.x * 256 + threadIdx.x;
    if (i >= n4) return;
    float4 v = reinterpret_cast<const float4*>(x)[i];
    float s = ni[i >> 5];              // 128 floats = 32 float4 per node
    v.x *= s; v.y *= s; v.z *= s; v.w *= s;
    reinterpret_cast<float4*>(h)[i] = v;
}

// ---------------------------------------------------------------- scatter: agg[dst] += relu(h[src]*w)
template<int D>
__global__ __launch_bounds__(256) void k_scatter(const int* __restrict__ ei,
                                                 const float* __restrict__ ew,
                                                 const float* __restrict__ h,
                                                 float* __restrict__ agg) {
    constexpr int TPE = D / 4;                       // threads per edge (float4 each)
    int e = blockIdx.x * (256 / TPE) + threadIdx.x / TPE;
    if (e >= NEDGES) return;
    int lane = threadIdx.x & (TPE - 1);
    int src = ei[e];
    int dst = ei[NEDGES + e];
    float w = ew[e];
    float4 v = *reinterpret_cast<const float4*>(h + (size_t)src * D + lane * 4);
    v.x = fmaxf(v.x * w, 0.f);
    v.y = fmaxf(v.y * w, 0.f);
    v.z = fmaxf(v.z * w, 0.f);
    v.w = fmaxf(v.w * w, 0.f);
    float* ap = agg + (size_t)dst * D + lane * 4;
    unsafeAtomicAdd(ap + 0, v.x);
    unsafeAtomicAdd(ap + 1, v.y);
    unsafeAtomicAdd(ap + 2, v.z);
    unsafeAtomicAdd(ap + 3, v.w);
}

// ---------------------------------------------------------------- fused GEMM
// C[M,Nn] = post( (FUSE_Z ? (1+eps)*A+Agg : A) @ B + bias )  with BN epilogue, optional ReLU
// BN params bnp layout: [4][Nn] = gamma, beta, mean, var
template<bool FUSE_Z, bool RELU>
__global__ __launch_bounds__(256) void k_gemm(
    const float* __restrict__ A, const float* __restrict__ Agg,
    const float* __restrict__ epsp,
    const float* __restrict__ B, const float* __restrict__ bias,
    const float* __restrict__ bnp,
    float* __restrict__ C, int M, int K, int Nn)
{
    __shared__ float As[16][64];   // k-major A tile
    __shared__ float Bs[16][64];
    const int tid = threadIdx.x;
    const int tx = tid & 15;       // col group
    const int ty = tid >> 4;       // row group
    const int row0 = blockIdx.y * 64;
    const int col0 = blockIdx.x * 64;
    const int ar = tid >> 2;            // 0..63: A row within tile
    const int ak = (tid & 3) << 2;      // 0,4,8,12: A k offset
    const int bkr = tid >> 4;           // 0..15: B k row
    const int bc = (tid & 15) << 2;     // B col offset

    float eps1 = 1.0f;
    if (FUSE_Z) eps1 = 1.0f + epsp[0];

    float acc[4][4] = {};

    for (int k0 = 0; k0 < K; k0 += 16) {
        float4 av = make_float4(0.f, 0.f, 0.f, 0.f);
        int arow = row0 + ar;
        if (arow < M) {
            av = *reinterpret_cast<const float4*>(A + (size_t)arow * K + k0 + ak);
            if (FUSE_Z) {
                float4 gv = *reinterpret_cast<const float4*>(Agg + (size_t)arow * K + k0 + ak);
                av.x = eps1 * av.x + gv.x;
                av.y = eps1 * av.y + gv.y;
                av.z = eps1 * av.z + gv.z;
                av.w = eps1 * av.w + gv.w;
            }
        }
        As[ak + 0][ar] = av.x;
        As[ak + 1][ar] = av.y;
        As[ak + 2][ar] = av.z;
        As[ak + 3][ar] = av.w;
        *reinterpret_cast<float4*>(&Bs[bkr][bc]) =
            *reinterpret_cast<const float4*>(B + (size_t)(k0 + bkr) * Nn + col0 + bc);
        __syncthreads();
        #pragma unroll
        for (int k = 0; k < 16; ++k) {
            float4 a = *reinterpret_cast<const float4*>(&As[k][ty << 2]);
            float4 b = *reinterpret_cast<const float4*>(&Bs[k][tx << 2]);
            acc[0][0] += a.x * b.x; acc[0][1] += a.x * b.y; acc[0][2] += a.x * b.z; acc[0][3] += a.x * b.w;
            acc[1][0] += a.y * b.x; acc[1][1] += a.y * b.y; acc[1][2] += a.y * b.z; acc[1][3] += a.y * b.w;
            acc[2][0] += a.z * b.x; acc[2][1] += a.z * b.y; acc[2][2] += a.z * b.z; acc[2][3] += a.z * b.w;
            acc[3][0] += a.w * b.x; acc[3][1] += a.w * b.y; acc[3][2] += a.w * b.z; acc[3][3] += a.w * b.w;
        }
        __syncthreads();
    }

    const int col = col0 + (tx << 2);
    float4 bi = *reinterpret_cast<const float4*>(bias + col);
    float4 ga = *reinterpret_cast<const float4*>(bnp + 0 * Nn + col);
    float4 be = *reinterpret_cast<const float4*>(bnp + 1 * Nn + col);
    float4 mu = *reinterpret_cast<const float4*>(bnp + 2 * Nn + col);
    float4 va = *reinterpret_cast<const float4*>(bnp + 3 * Nn + col);
    float s0 = ga.x * rsqrtf(va.x + 1e-5f);
    float s1 = ga.y * rsqrtf(va.y + 1e-5f);
    float s2 = ga.z * rsqrtf(va.z + 1e-5f);
    float s3 = ga.w * rsqrtf(va.w + 1e-5f);
    float h0 = be.x - mu.x * s0;
    float h1 = be.y - mu.y * s1;
    float h2 = be.z - mu.z * s2;
    float h3 = be.w - mu.w * s3;

    #pragma unroll
    for (int i = 0; i < 4; ++i) {
        int row = row0 + (ty << 2) + i;
        if (row >= M) break;
        float4 o;
        o.x = (acc[i][0] + bi.x) * s0 + h0;
        o.y = (acc[i][1] + bi.y) * s1 + h1;
        o.z = (acc[i][2] + bi.z) * s2 + h2;
        o.w = (acc[i][3] + bi.w) * s3 + h3;
        if (RELU) {
            o.x = fmaxf(o.x, 0.f);
            o.y = fmaxf(o.y, 0.f);
            o.z = fmaxf(o.z, 0.f);
            o.w = fmaxf(o.w, 0.f);
        }
        *reinterpret_cast<float4*>(C + (size_t)row * Nn + col) = o;
    }
}

// ---------------------------------------------------------------- node_key = sigmoid(h @ attW + attb)
__global__ __launch_bounds__(256) void k_att(const float* __restrict__ h,
                                             const float* __restrict__ attW,
                                             const float* __restrict__ attb,
                                             float* __restrict__ nk) {
    int wid = (blockIdx.x * 256 + threadIdx.x) >> 6;
    int lane = threadIdx.x & 63;
    if (wid >= NNODES) return;
    float4 v = *reinterpret_cast<const float4*>(h + (size_t)wid * 256 + lane * 4);
    float4 w = *reinterpret_cast<const float4*>(attW + lane * 4);
    float s = v.x * w.x + v.y * w.y + v.z * w.z + v.w * w.w;
    #pragma unroll
    for (int off = 32; off > 0; off >>= 1) s += __shfl_xor(s, off);
    if (lane == 0) {
        s += attb[0];
        nk[wid] = 1.f / (1.f + expf(-s));
    }
}

// ---------------------------------------------------------------- edge_key = nk[src]*nk[dst]
__global__ __launch_bounds__(256) void k_edge(const int* __restrict__ ei,
                                              const float* __restrict__ nk,
                                              float* __restrict__ ek) {
    int e = blockIdx.x * 256 + threadIdx.x;
    if (e >= NEDGES) return;
    ek[e] = nk[ei[e]] * nk[ei[NEDGES + e]];
}

// ----------------------------------------------------------------
extern "C" void kernel_launch(void* const* d_in, const int* in_sizes, int n_in,
                              void* d_out, int out_size, void* d_ws, size_t ws_size,
                              hipStream_t stream) {
    const float* x        = (const float*)d_in[0];
    const int*   ei       = (const int*)d_in[1];
    const float* node_imp = (const float*)d_in[2];
    const float* edge_imp = (const float*)d_in[3];
    const float* c0_W1    = (const float*)d_in[4];
    const float* c0_b1    = (const float*)d_in[5];
    const float* c0_bn    = (const float*)d_in[6];
    const float* c0_W2    = (const float*)d_in[7];
    const float* c0_b2    = (const float*)d_in[8];
    const float* c0_eps   = (const float*)d_in[9];
    const float* cs_W1    = (const float*)d_in[10];
    const float* cs_b1    = (const float*)d_in[11];
    const float* cs_bn    = (const float*)d_in[12];
    const float* cs_W2    = (const float*)d_in[13];
    const float* cs_b2    = (const float*)d_in[14];
    const float* cs_eps   = (const float*)d_in[15];
    const float* obn      = (const float*)d_in[16];
    const float* att_W    = (const float*)d_in[17];
    const float* att_b    = (const float*)d_in[18];
    float* out = (float*)d_out;

    float* h   = (float*)d_ws;                       // N*256
    float* agg = h + (size_t)NNODES * 256;           // N*256
    float* t   = agg + (size_t)NNODES * 256;         // N*512

    const int M = NNODES;
    dim3 blk(256);
    dim3 g1(512 / 64, (M + 63) / 64);   // GEMM1 grid (Nn=512)
    dim3 g2(256 / 64, (M + 63) / 64);   // GEMM2 grid (Nn=256)

    // ---- layer 0 (d_in = 128)
    {
        int n4 = NNODES * 128 / 4;
        k_premul<<<(n4 + 255) / 256, blk, 0, stream>>>(x, node_imp, h, n4);
        hipMemsetAsync(agg, 0, (size_t)NNODES * 128 * sizeof(float), stream);
        k_scatter<128><<<(NEDGES * 32 + 255) / 256, blk, 0, stream>>>(ei, edge_imp, h, agg);
        k_gemm<true, true><<<g1, blk, 0, stream>>>(h, agg, c0_eps, c0_W1, c0_b1, c0_bn, t, M, 128, 512);
        k_gemm<false, true><<<g2, blk, 0, stream>>>(t, nullptr, nullptr, c0_W2, c0_b2, obn, h, M, 512, 256);
    }
    // ---- layers 1,2 (d_in = 256)
    for (int i = 0; i < 2; ++i) {
        hipMemsetAsync(agg, 0, (size_t)NNODES * 256 * sizeof(float), stream);
        k_scatter<256><<<(NEDGES * 64 + 255) / 256, blk, 0, stream>>>(ei, edge_imp, h, agg);
        const float* W1 = cs_W1 + (size_t)i * 256 * 512;
        const float* b1 = cs_b1 + (size_t)i * 512;
        const float* bn1 = cs_bn + (size_t)i * 4 * 512;
        const float* W2 = cs_W2 + (size_t)i * 512 * 256;
        const float* b2 = cs_b2 + (size_t)i * 256;
        const float* ob = obn + (size_t)(i + 1) * 4 * 256;
        k_gemm<true, true><<<g1, blk, 0, stream>>>(h, agg, cs_eps + i, W1, b1, bn1, t, M, 256, 512);
        if (i == 0)
            k_gemm<false, true><<<g2, blk, 0, stream>>>(t, nullptr, nullptr, W2, b2, ob, h, M, 512, 256);
        else
            k_gemm<false, false><<<g2, blk, 0, stream>>>(t, nullptr, nullptr, W2, b2, ob, h, M, 512, 256);
    }
    // ---- attention + edge keys
    k_att<<<(NNODES * 64 + 255) / 256, blk, 0, stream>>>(h, att_W, att_b, out);
    k_edge<<<(NEDGES + 255) / 256, blk, 0, stream>>>(ei, out, out + NNODES);
}

// Round 2
// 746.788 us; speedup vs baseline: 4.3474x; 4.3474x over previous
//
#include <hip/hip_runtime.h>
#include <math.h>

#define NNODES 20000
#define NEDGES 320000

// ================================================================ CSR build
__global__ __launch_bounds__(256) void k_hist(const int* __restrict__ dst,
                                              int* __restrict__ cnt) {
    int e = blockIdx.x * 256 + threadIdx.x;
    if (e >= NEDGES) return;
    atomicAdd(&cnt[dst[e]], 1);
}

// single-block exclusive scan of cnt[N] -> off[N]
__global__ __launch_bounds__(1024) void k_scan(const int* __restrict__ cnt,
                                               int* __restrict__ off) {
    __shared__ int part[1024];
    const int tid = threadIdx.x;
    constexpr int PER = (NNODES + 1023) / 1024;   // 20
    const int base = tid * PER;
    int local[PER];
    int sum = 0;
    #pragma unroll
    for (int i = 0; i < PER; ++i) {
        int idx = base + i;
        int c = (idx < NNODES) ? cnt[idx] : 0;
        local[i] = sum;
        sum += c;
    }
    part[tid] = sum;
    __syncthreads();
    for (int d = 1; d < 1024; d <<= 1) {
        int v = (tid >= d) ? part[tid - d] : 0;
        __syncthreads();
        if (tid >= d) part[tid] += v;
        __syncthreads();
    }
    int prefix = (tid == 0) ? 0 : part[tid - 1];
    #pragma unroll
    for (int i = 0; i < PER; ++i) {
        int idx = base + i;
        if (idx < NNODES) off[idx] = prefix + local[i];
    }
}

// fill permutation; mutates off[i] from start-of-node-i into end-of-node-i
__global__ __launch_bounds__(256) void k_fill(const int* __restrict__ dst,
                                              int* __restrict__ off,
                                              int* __restrict__ perm) {
    int e = blockIdx.x * 256 + threadIdx.x;
    if (e >= NEDGES) return;
    int p = atomicAdd(&off[dst[e]], 1);
    perm[p] = e;
}

// ================================================================ aggregation (gather)
// z[node] = (1+eps)*h[node] + sum_{e: dst=node} relu(h[src]*ew)
// layer 0 variant: h = x * node_imp computed on the fly, D=128
__global__ __launch_bounds__(256) void k_agg0(const int* __restrict__ src,
                                              const float* __restrict__ ew,
                                              const float* __restrict__ x,
                                              const float* __restrict__ ni,
                                              const float* __restrict__ epsp,
                                              const int* __restrict__ off,
                                              const int* __restrict__ perm,
                                              float* __restrict__ z) {
    int node = (blockIdx.x * 256 + threadIdx.x) >> 5;   // 32 threads/node
    int lane = threadIdx.x & 31;
    if (node >= NNODES) return;
    const float eps1 = 1.0f + epsp[0];
    int p0 = (node == 0) ? 0 : off[node - 1];
    int p1 = off[node];
    float4 hv = *reinterpret_cast<const float4*>(x + (size_t)node * 128 + lane * 4);
    float sn = eps1 * ni[node];
    float4 acc;
    acc.x = sn * hv.x; acc.y = sn * hv.y; acc.z = sn * hv.z; acc.w = sn * hv.w;
    for (int p = p0; p < p1; ++p) {
        int eid = perm[p];
        int s = src[eid];
        float w = ew[eid] * ni[s];
        float4 v = *reinterpret_cast<const float4*>(x + (size_t)s * 128 + lane * 4);
        acc.x += fmaxf(v.x * w, 0.f);
        acc.y += fmaxf(v.y * w, 0.f);
        acc.z += fmaxf(v.z * w, 0.f);
        acc.w += fmaxf(v.w * w, 0.f);
    }
    *reinterpret_cast<float4*>(z + (size_t)node * 128 + lane * 4) = acc;
}

// layers 1,2: D=256, one wave per node
__global__ __launch_bounds__(256) void k_agg256(const int* __restrict__ src,
                                                const float* __restrict__ ew,
                                                const float* __restrict__ h,
                                                const float* __restrict__ epsp,
                                                const int* __restrict__ off,
                                                const int* __restrict__ perm,
                                                float* __restrict__ z) {
    int node = (blockIdx.x * 256 + threadIdx.x) >> 6;   // 64 threads/node
    int lane = threadIdx.x & 63;
    if (node >= NNODES) return;
    const float eps1 = 1.0f + epsp[0];
    int p0 = (node == 0) ? 0 : off[node - 1];
    int p1 = off[node];
    float4 hv = *reinterpret_cast<const float4*>(h + (size_t)node * 256 + lane * 4);
    float4 acc;
    acc.x = eps1 * hv.x; acc.y = eps1 * hv.y; acc.z = eps1 * hv.z; acc.w = eps1 * hv.w;
    for (int p = p0; p < p1; ++p) {
        int eid = perm[p];
        int s = src[eid];
        float w = ew[eid];
        float4 v = *reinterpret_cast<const float4*>(h + (size_t)s * 256 + lane * 4);
        acc.x += fmaxf(v.x * w, 0.f);
        acc.y += fmaxf(v.y * w, 0.f);
        acc.z += fmaxf(v.z * w, 0.f);
        acc.w += fmaxf(v.w * w, 0.f);
    }
    *reinterpret_cast<float4*>(z + (size_t)node * 256 + lane * 4) = acc;
}

// ================================================================ fused GEMM
// C[M,Nn] = post( A @ B + bias ) with BN epilogue, optional ReLU
// bnp layout: [4][Nn] = gamma, beta, mean, var
template<bool RELU>
__global__ __launch_bounds__(256) void k_gemm(
    const float* __restrict__ A,
    const float* __restrict__ B, const float* __restrict__ bias,
    const float* __restrict__ bnp,
    float* __restrict__ C, int M, int K, int Nn)
{
    __shared__ float As[16][64];   // k-major A tile
    __shared__ float Bs[16][64];
    const int tid = threadIdx.x;
    const int tx = tid & 15;
    const int ty = tid >> 4;
    const int row0 = blockIdx.y * 64;
    const int col0 = blockIdx.x * 64;
    const int ar = tid >> 2;
    const int ak = (tid & 3) << 2;
    const int bkr = tid >> 4;
    const int bc = (tid & 15) << 2;

    float acc[4][4] = {};

    for (int k0 = 0; k0 < K; k0 += 16) {
        float4 av = make_float4(0.f, 0.f, 0.f, 0.f);
        int arow = row0 + ar;
        if (arow < M)
            av = *reinterpret_cast<const float4*>(A + (size_t)arow * K + k0 + ak);
        As[ak + 0][ar] = av.x;
        As[ak + 1][ar] = av.y;
        As[ak + 2][ar] = av.z;
        As[ak + 3][ar] = av.w;
        *reinterpret_cast<float4*>(&Bs[bkr][bc]) =
            *reinterpret_cast<const float4*>(B + (size_t)(k0 + bkr) * Nn + col0 + bc);
        __syncthreads();
        #pragma unroll
        for (int k = 0; k < 16; ++k) {
            float4 a = *reinterpret_cast<const float4*>(&As[k][ty << 2]);
            float4 b = *reinterpret_cast<const float4*>(&Bs[k][tx << 2]);
            acc[0][0] += a.x * b.x; acc[0][1] += a.x * b.y; acc[0][2] += a.x * b.z; acc[0][3] += a.x * b.w;
            acc[1][0] += a.y * b.x; acc[1][1] += a.y * b.y; acc[1][2] += a.y * b.z; acc[1][3] += a.y * b.w;
            acc[2][0] += a.z * b.x; acc[2][1] += a.z * b.y; acc[2][2] += a.z * b.z; acc[2][3] += a.z * b.w;
            acc[3][0] += a.w * b.x; acc[3][1] += a.w * b.y; acc[3][2] += a.w * b.z; acc[3][3] += a.w * b.w;
        }
        __syncthreads();
    }

    const int col = col0 + (tx << 2);
    float4 bi = *reinterpret_cast<const float4*>(bias + col);
    float4 ga = *reinterpret_cast<const float4*>(bnp + 0 * Nn + col);
    float4 be = *reinterpret_cast<const float4*>(bnp + 1 * Nn + col);
    float4 mu = *reinterpret_cast<const float4*>(bnp + 2 * Nn + col);
    float4 va = *reinterpret_cast<const float4*>(bnp + 3 * Nn + col);
    float s0 = ga.x * rsqrtf(va.x + 1e-5f);
    float s1 = ga.y * rsqrtf(va.y + 1e-5f);
    float s2 = ga.z * rsqrtf(va.z + 1e-5f);
    float s3 = ga.w * rsqrtf(va.w + 1e-5f);
    float h0 = be.x - mu.x * s0;
    float h1 = be.y - mu.y * s1;
    float h2 = be.z - mu.z * s2;
    float h3 = be.w - mu.w * s3;

    #pragma unroll
    for (int i = 0; i < 4; ++i) {
        int row = row0 + (ty << 2) + i;
        if (row >= M) break;
        float4 o;
        o.x = (acc[i][0] + bi.x) * s0 + h0;
        o.y = (acc[i][1] + bi.y) * s1 + h1;
        o.z = (acc[i][2] + bi.z) * s2 + h2;
        o.w = (acc[i][3] + bi.w) * s3 + h3;
        if (RELU) {
            o.x = fmaxf(o.x, 0.f);
            o.y = fmaxf(o.y, 0.f);
            o.z = fmaxf(o.z, 0.f);
            o.w = fmaxf(o.w, 0.f);
        }
        *reinterpret_cast<float4*>(C + (size_t)row * Nn + col) = o;
    }
}

// ================================================================ attention + edges
__global__ __launch_bounds__(256) void k_att(const float* __restrict__ h,
                                             const float* __restrict__ attW,
                                             const float* __restrict__ attb,
                                             float* __restrict__ nk) {
    int wid = (blockIdx.x * 256 + threadIdx.x) >> 6;
    int lane = threadIdx.x & 63;
    if (wid >= NNODES) return;
    float4 v = *reinterpret_cast<const float4*>(h + (size_t)wid * 256 + lane * 4);
    float4 w = *reinterpret_cast<const float4*>(attW + lane * 4);
    float s = v.x * w.x + v.y * w.y + v.z * w.z + v.w * w.w;
    #pragma unroll
    for (int off = 32; off > 0; off >>= 1) s += __shfl_xor(s, off);
    if (lane == 0) {
        s += attb[0];
        nk[wid] = 1.f / (1.f + expf(-s));
    }
}

__global__ __launch_bounds__(256) void k_edge(const int* __restrict__ ei,
                                              const float* __restrict__ nk,
                                              float* __restrict__ ek) {
    int e = blockIdx.x * 256 + threadIdx.x;
    if (e >= NEDGES) return;
    ek[e] = nk[ei[e]] * nk[ei[NEDGES + e]];
}

// ================================================================
extern "C" void kernel_launch(void* const* d_in, const int* in_sizes, int n_in,
                              void* d_out, int out_size, void* d_ws, size_t ws_size,
                              hipStream_t stream) {
    const float* x        = (const float*)d_in[0];
    const int*   ei       = (const int*)d_in[1];
    const float* node_imp = (const float*)d_in[2];
    const float* edge_imp = (const float*)d_in[3];
    const float* c0_W1    = (const float*)d_in[4];
    const float* c0_b1    = (const float*)d_in[5];
    const float* c0_bn    = (const float*)d_in[6];
    const float* c0_W2    = (const float*)d_in[7];
    const float* c0_b2    = (const float*)d_in[8];
    const float* c0_eps   = (const float*)d_in[9];
    const float* cs_W1    = (const float*)d_in[10];
    const float* cs_b1    = (const float*)d_in[11];
    const float* cs_bn    = (const float*)d_in[12];
    const float* cs_W2    = (const float*)d_in[13];
    const float* cs_b2    = (const float*)d_in[14];
    const float* cs_eps   = (const float*)d_in[15];
    const float* obn      = (const float*)d_in[16];
    const float* att_W    = (const float*)d_in[17];
    const float* att_b    = (const float*)d_in[18];
    float* out = (float*)d_out;

    const int* e_src = ei;
    const int* e_dst = ei + NEDGES;

    // float workspace (same footprint as round 0: N*1024 floats)
    float* h = (float*)d_ws;                       // N*256
    float* z = h + (size_t)NNODES * 256;           // N*256 (layer0 uses N*128)
    float* t = z + (size_t)NNODES * 256;           // N*512

    // int scratch: cnt aliases h (dead before h is first written);
    // perm + off live in d_out (dead before k_att/k_edge write it)
    int* cnt  = (int*)h;                           // N ints
    int* perm = (int*)d_out;                       // E ints
    int* off  = (int*)d_out + NEDGES;              // N ints

    const int M = NNODES;
    dim3 blk(256);
    dim3 g1(512 / 64, (M + 63) / 64);
    dim3 g2(256 / 64, (M + 63) / 64);
    const int eb = (NEDGES + 255) / 256;

    // ---- CSR build (per call; graph identical across layers)
    hipMemsetAsync(cnt, 0, NNODES * sizeof(int), stream);
    k_hist<<<eb, blk, 0, stream>>>(e_dst, cnt);
    k_scan<<<1, 1024, 0, stream>>>(cnt, off);
    k_fill<<<eb, blk, 0, stream>>>(e_dst, off, perm);

    // ---- layer 0 (d=128)
    k_agg0<<<(NNODES * 32 + 255) / 256, blk, 0, stream>>>(e_src, edge_imp, x, node_imp,
                                                          c0_eps, off, perm, z);
    k_gemm<true><<<g1, blk, 0, stream>>>(z, c0_W1, c0_b1, c0_bn, t, M, 128, 512);
    k_gemm<true><<<g2, blk, 0, stream>>>(t, c0_W2, c0_b2, obn, h, M, 512, 256);

    // ---- layers 1,2 (d=256)
    for (int i = 0; i < 2; ++i) {
        k_agg256<<<(NNODES * 64 + 255) / 256, blk, 0, stream>>>(e_src, edge_imp, h,
                                                                cs_eps + i, off, perm, z);
        const float* W1  = cs_W1 + (size_t)i * 256 * 512;
        const float* b1  = cs_b1 + (size_t)i * 512;
        const float* bn1 = cs_bn + (size_t)i * 4 * 512;
        const float* W2  = cs_W2 + (size_t)i * 512 * 256;
        const float* b2  = cs_b2 + (size_t)i * 256;
        const float* ob  = obn + (size_t)(i + 1) * 4 * 256;
        k_gemm<true><<<g1, blk, 0, stream>>>(z, W1, b1, bn1, t, M, 256, 512);
        if (i == 0)
            k_gemm<true><<<g2, blk, 0, stream>>>(t, W2, b2, ob, h, M, 512, 256);
        else
            k_gemm<false><<<g2, blk, 0, stream>>>(t, W2, b2, ob, h, M, 512, 256);
    }

    // ---- attention + edge keys (perm/off in d_out are dead now)
    k_att<<<(NNODES * 64 + 255) / 256, blk, 0, stream>>>(h, att_W, att_b, out);
    k_edge<<<eb, blk, 0, stream>>>(ei, out, out + NNODES);
}

// Round 3
// 266.450 us; speedup vs baseline: 12.1845x; 2.8027x over previous
//
#include <hip/hip_runtime.h>
#include <math.h>

#define NNODES 20000
#define NEDGES 320000
#define MPAD   20096          // 157 * 128
#define BM 128
#define BN 128
#define BK 64

typedef __attribute__((ext_vector_type(8))) short bf16x8;
typedef __attribute__((ext_vector_type(4))) float f32x4;

__device__ __forceinline__ short f2bf(float f) {
    unsigned u = __builtin_bit_cast(unsigned, f);
    u += 0x7fff + ((u >> 16) & 1);
    return (short)(u >> 16);
}
__device__ __forceinline__ float bf2f(unsigned short u) {
    return __builtin_bit_cast(float, (unsigned)u << 16);
}
__device__ __forceinline__ void gload16(const void* g, void* l) {
    __builtin_amdgcn_global_load_lds((const __attribute__((address_space(1))) void*)g,
                                     (__attribute__((address_space(3))) void*)l, 16, 0, 0);
}

// ================================================================ CSR build
__global__ __launch_bounds__(256) void k_hist(const int* __restrict__ dst,
                                              int* __restrict__ cnt) {
    int e = blockIdx.x * 256 + threadIdx.x;
    if (e >= NEDGES) return;
    atomicAdd(&cnt[dst[e]], 1);
}

__global__ __launch_bounds__(1024) void k_scan(const int* __restrict__ cnt,
                                               int* __restrict__ off) {
    __shared__ int part[1024];
    const int tid = threadIdx.x;
    constexpr int PER = (NNODES + 1023) / 1024;   // 20
    const int base = tid * PER;
    int local[PER];
    int sum = 0;
    #pragma unroll
    for (int i = 0; i < PER; ++i) {
        int idx = base + i;
        int c = (idx < NNODES) ? cnt[idx] : 0;
        local[i] = sum;
        sum += c;
    }
    part[tid] = sum;
    __syncthreads();
    for (int d = 1; d < 1024; d <<= 1) {
        int v = (tid >= d) ? part[tid - d] : 0;
        __syncthreads();
        if (tid >= d) part[tid] += v;
        __syncthreads();
    }
    int prefix = (tid == 0) ? 0 : part[tid - 1];
    #pragma unroll
    for (int i = 0; i < PER; ++i) {
        int idx = base + i;
        if (idx < NNODES) off[idx] = prefix + local[i];
    }
}

// fill CSR-ordered src ids and edge weights; off[i] becomes end-of-node-i
__global__ __launch_bounds__(256) void k_fill(const int* __restrict__ dst,
                                              const int* __restrict__ src,
                                              const float* __restrict__ ew,
                                              int* __restrict__ off,
                                              int* __restrict__ srcs,
                                              float* __restrict__ ews) {
    int e = blockIdx.x * 256 + threadIdx.x;
    if (e >= NEDGES) return;
    int p = atomicAdd(&off[dst[e]], 1);
    srcs[p] = src[e];
    ews[p] = ew[e];
}

// ================================================================ weight prep: fp32 [K][N] -> bf16 [N][K]
__global__ __launch_bounds__(256) void k_prep(const float* __restrict__ c0W1,
                                              const float* __restrict__ csW1,
                                              const float* __restrict__ c0W2,
                                              const float* __restrict__ csW2,
                                              short* __restrict__ wT) {
    int i = blockIdx.x * 256 + threadIdx.x;
    if (i >= 720896) return;
    const float* src; int K, N2, base;
    if (i < 65536)       { src = c0W1;          base = 0;      K = 128; N2 = 512; }
    else if (i < 196608) { src = csW1;          base = 65536;  K = 256; N2 = 512; }
    else if (i < 327680) { src = csW1 + 131072; base = 196608; K = 256; N2 = 512; }
    else if (i < 458752) { src = c0W2;          base = 327680; K = 512; N2 = 256; }
    else if (i < 589824) { src = csW2;          base = 458752; K = 512; N2 = 256; }
    else                 { src = csW2 + 131072; base = 589824; K = 512; N2 = 256; }
    int j = i - base;
    int n = j / K, k = j - n * K;
    wT[i] = f2bf(src[(size_t)k * N2 + n]);
}

// ================================================================ aggregation (gather, bf16)
// layer 0: z[n] = (1+eps)*x[n]*ni[n] + sum relu(x[s]*ni[s]*ew); D=128, 32 lanes x 4 ch
__global__ __launch_bounds__(256) void k_agg0(const int* __restrict__ srcs,
                                              const float* __restrict__ ews,
                                              const float* __restrict__ x,
                                              const float* __restrict__ ni,
                                              const float* __restrict__ epsp,
                                              const int* __restrict__ off,
                                              short* __restrict__ z) {
    int node = (blockIdx.x * 256 + threadIdx.x) >> 5;
    int lane = threadIdx.x & 31;
    if (node >= NNODES) return;
    const float eps1 = 1.0f + epsp[0];
    int p0 = (node == 0) ? 0 : off[node - 1];
    int p1 = off[node];
    float4 hv = *reinterpret_cast<const float4*>(x + (size_t)node * 128 + lane * 4);
    float sn = eps1 * ni[node];
    float a0 = sn * hv.x, a1 = sn * hv.y, a2 = sn * hv.z, a3 = sn * hv.w;
    for (int p = p0; p < p1; ++p) {
        int s = srcs[p];
        float w = ews[p] * ni[s];
        float4 v = *reinterpret_cast<const float4*>(x + (size_t)s * 128 + lane * 4);
        a0 += fmaxf(v.x * w, 0.f);
        a1 += fmaxf(v.y * w, 0.f);
        a2 += fmaxf(v.z * w, 0.f);
        a3 += fmaxf(v.w * w, 0.f);
    }
    short4 o;
    o.x = f2bf(a0); o.y = f2bf(a1); o.z = f2bf(a2); o.w = f2bf(a3);
    *reinterpret_cast<short4*>(z + (size_t)node * 128 + lane * 4) = o;
}

// layers 1,2: D=256 bf16, 32 lanes x 8 ch
__global__ __launch_bounds__(256) void k_agg256(const int* __restrict__ srcs,
                                                const float* __restrict__ ews,
                                                const short* __restrict__ h,
                                                const float* __restrict__ epsp,
                                                const int* __restrict__ off,
                                                short* __restrict__ z) {
    int node = (blockIdx.x * 256 + threadIdx.x) >> 5;
    int lane = threadIdx.x & 31;
    if (node >= NNODES) return;
    const float eps1 = 1.0f + epsp[0];
    int p0 = (node == 0) ? 0 : off[node - 1];
    int p1 = off[node];
    uint4 hv = *reinterpret_cast<const uint4*>(h + (size_t)node * 256 + lane * 8);
    float acc[8];
    {
        const unsigned w0 = hv.x, w1 = hv.y, w2 = hv.z, w3 = hv.w;
        acc[0] = eps1 * __builtin_bit_cast(float, w0 << 16);
        acc[1] = eps1 * __builtin_bit_cast(float, w0 & 0xffff0000u);
        acc[2] = eps1 * __builtin_bit_cast(float, w1 << 16);
        acc[3] = eps1 * __builtin_bit_cast(float, w1 & 0xffff0000u);
        acc[4] = eps1 * __builtin_bit_cast(float, w2 << 16);
        acc[5] = eps1 * __builtin_bit_cast(float, w2 & 0xffff0000u);
        acc[6] = eps1 * __builtin_bit_cast(float, w3 << 16);
        acc[7] = eps1 * __builtin_bit_cast(float, w3 & 0xffff0000u);
    }
    for (int p = p0; p < p1; ++p) {
        int s = srcs[p];
        float w = ews[p];
        uint4 v = *reinterpret_cast<const uint4*>(h + (size_t)s * 256 + lane * 8);
        acc[0] += fmaxf(__builtin_bit_cast(float, v.x << 16) * w, 0.f);
        acc[1] += fmaxf(__builtin_bit_cast(float, v.x & 0xffff0000u) * w, 0.f);
        acc[2] += fmaxf(__builtin_bit_cast(float, v.y << 16) * w, 0.f);
        acc[3] += fmaxf(__builtin_bit_cast(float, v.y & 0xffff0000u) * w, 0.f);
        acc[4] += fmaxf(__builtin_bit_cast(float, v.z << 16) * w, 0.f);
        acc[5] += fmaxf(__builtin_bit_cast(float, v.z & 0xffff0000u) * w, 0.f);
        acc[6] += fmaxf(__builtin_bit_cast(float, v.w << 16) * w, 0.f);
        acc[7] += fmaxf(__builtin_bit_cast(float, v.w & 0xffff0000u) * w, 0.f);
    }
    ushort oe[8];
    #pragma unroll
    for (int j = 0; j < 8; ++j) oe[j] = (ushort)f2bf(acc[j]);
    uint4 ov;
    ov.x = oe[0] | ((unsigned)oe[1] << 16);
    ov.y = oe[2] | ((unsigned)oe[3] << 16);
    ov.z = oe[4] | ((unsigned)oe[5] << 16);
    ov.w = oe[6] | ((unsigned)oe[7] << 16);
    *reinterpret_cast<uint4*>(z + (size_t)node * 256 + lane * 8) = ov;
}

// ================================================================ bf16 MFMA GEMM
// C[MPAD][Nn] = post( A[MPAD][K] @ BT[Nn][K]^T + bias ), BN epilogue, opt ReLU
template<bool RELU>
__global__ __launch_bounds__(256) void k_gemm(
    const short* __restrict__ A,
    const short* __restrict__ BT,
    const float* __restrict__ bias,
    const float* __restrict__ bnp,   // [4][Nn]
    short* __restrict__ C, int K, int Nn)
{
    __shared__ __align__(16) short As[BM * BK];
    __shared__ __align__(16) short Bs[BN * BK];
    const int tid = threadIdx.x;
    const int lane = tid & 63;
    const int wid = tid >> 6;
    const int wr = wid >> 1, wc = wid & 1;     // 2x2 waves, 64x64 each
    const int row0 = blockIdx.y * BM;
    const int col0 = blockIdx.x * BN;
    const int srow = tid >> 3;                 // 0..31 staging row
    const int schunk = tid & 7;                // 16B chunk slot

    f32x4 acc[4][4];
    #pragma unroll
    for (int m = 0; m < 4; ++m)
        #pragma unroll
        for (int n = 0; n < 4; ++n)
            acc[m][n] = (f32x4){0.f, 0.f, 0.f, 0.f};

    for (int kt = 0; kt < K; kt += BK) {
        #pragma unroll
        for (int s = 0; s < 4; ++s) {
            int r = s * 32 + srow;
            int sc = schunk ^ (r & 7);         // pre-swizzled global source chunk
            gload16(A + (size_t)(row0 + r) * K + kt + sc * 8,
                    (char*)As + s * 4096 + tid * 16);
        }
        #pragma unroll
        for (int s = 0; s < 4; ++s) {
            int r = s * 32 + srow;
            int sc = schunk ^ (r & 7);
            gload16(BT + (size_t)(col0 + r) * K + kt + sc * 8,
                    (char*)Bs + s * 4096 + tid * 16);
        }
        __syncthreads();   // compiler drains vmcnt before barrier
        #pragma unroll
        for (int ks = 0; ks < 2; ++ks) {
            bf16x8 af[4], bfr[4];
            #pragma unroll
            for (int m = 0; m < 4; ++m) {
                int r = wr * 64 + m * 16 + (lane & 15);
                int c = (ks * 4 + (lane >> 4)) ^ (r & 7);
                af[m] = *(const bf16x8*)((const char*)As + r * 128 + c * 16);
            }
            #pragma unroll
            for (int n = 0; n < 4; ++n) {
                int r = wc * 64 + n * 16 + (lane & 15);
                int c = (ks * 4 + (lane >> 4)) ^ (r & 7);
                bfr[n] = *(const bf16x8*)((const char*)Bs + r * 128 + c * 16);
            }
            #pragma unroll
            for (int m = 0; m < 4; ++m)
                #pragma unroll
                for (int n = 0; n < 4; ++n)
                    acc[m][n] = __builtin_amdgcn_mfma_f32_16x16x32_bf16(af[m], bfr[n], acc[m][n], 0, 0, 0);
        }
        __syncthreads();
    }

    // epilogue: col = col0 + wc*64 + n*16 + (lane&15); row = row0 + wr*64 + m*16 + 4*(lane>>4)+j
    const int cb = col0 + wc * 64 + (lane & 15);
    float scl[4], shf[4];
    #pragma unroll
    for (int n = 0; n < 4; ++n) {
        int c = cb + n * 16;
        float ga = bnp[c], be = bnp[Nn + c], mu = bnp[2 * Nn + c], va = bnp[3 * Nn + c];
        float s = ga * rsqrtf(va + 1e-5f);
        scl[n] = s;
        shf[n] = be - mu * s + bias[c] * s;
    }
    const int rb = row0 + wr * 64 + 4 * (lane >> 4);
    #pragma unroll
    for (int m = 0; m < 4; ++m) {
        #pragma unroll
        for (int j = 0; j < 4; ++j) {
            int r = rb + m * 16 + j;
            #pragma unroll
            for (int n = 0; n < 4; ++n) {
                float o = acc[m][n][j] * scl[n] + shf[n];
                if (RELU) o = fmaxf(o, 0.f);
                C[(size_t)r * Nn + cb + n * 16] = f2bf(o);
            }
        }
    }
}

// ================================================================ attention + edges
__global__ __launch_bounds__(256) void k_att(const short* __restrict__ h,
                                             const float* __restrict__ attW,
                                             const float* __restrict__ attb,
                                             float* __restrict__ nk) {
    int wid = (blockIdx.x * 256 + threadIdx.x) >> 6;
    int lane = threadIdx.x & 63;
    if (wid >= NNODES) return;
    ushort4 v = *reinterpret_cast<const ushort4*>(h + (size_t)wid * 256 + lane * 4);
    float4 w = reinterpret_cast<const float4*>(attW)[lane];
    float s = bf2f(v.x) * w.x + bf2f(v.y) * w.y + bf2f(v.z) * w.z + bf2f(v.w) * w.w;
    #pragma unroll
    for (int o = 32; o > 0; o >>= 1) s += __shfl_xor(s, o);
    if (lane == 0) {
        s += attb[0];
        nk[wid] = 1.f / (1.f + expf(-s));
    }
}

__global__ __launch_bounds__(256) void k_edge(const int* __restrict__ ei,
                                              const float* __restrict__ nk,
                                              float* __restrict__ ek) {
    int e = blockIdx.x * 256 + threadIdx.x;
    if (e >= NEDGES) return;
    ek[e] = nk[ei[e]] * nk[ei[NEDGES + e]];
}

// ================================================================
extern "C" void kernel_launch(void* const* d_in, const int* in_sizes, int n_in,
                              void* d_out, int out_size, void* d_ws, size_t ws_size,
                              hipStream_t stream) {
    const float* x        = (const float*)d_in[0];
    const int*   ei       = (const int*)d_in[1];
    const float* node_imp = (const float*)d_in[2];
    const float* edge_imp = (const float*)d_in[3];
    const float* c0_W1    = (const float*)d_in[4];
    const float* c0_b1    = (const float*)d_in[5];
    const float* c0_bn    = (const float*)d_in[6];
    const float* c0_W2    = (const float*)d_in[7];
    const float* c0_b2    = (const float*)d_in[8];
    const float* c0_eps   = (const float*)d_in[9];
    const float* cs_W1    = (const float*)d_in[10];
    const float* cs_b1    = (const float*)d_in[11];
    const float* cs_bn    = (const float*)d_in[12];
    const float* cs_W2    = (const float*)d_in[13];
    const float* cs_b2    = (const float*)d_in[14];
    const float* cs_eps   = (const float*)d_in[15];
    const float* obn      = (const float*)d_in[16];
    const float* att_W    = (const float*)d_in[17];
    const float* att_b    = (const float*)d_in[18];
    float* out = (float*)d_out;

    const int* e_src = ei;
    const int* e_dst = ei + NEDGES;

    // workspace layout (bf16 activations + prepped weights + CSR arrays)
    short* zB = (short*)d_ws;                   // [MPAD][256] (layer0 uses 128)
    short* tB = zB + (size_t)MPAD * 256;        // [MPAD][512]
    short* hB = tB + (size_t)MPAD * 512;        // [MPAD][256]
    short* wT = hB + (size_t)MPAD * 256;        // 720896 bf16
    int*   srcs = (int*)(wT + 720896);          // E
    float* ews  = (float*)(srcs + NEDGES);      // E
    int*   cnt  = (int*)(ews + NEDGES);         // N
    int*   off  = (int*)d_out;                  // N (dead before k_att writes)

    const short* WT_c0W1  = wT + 0;        // [512][128]
    const short* WT_cs1_0 = wT + 65536;    // [512][256]
    const short* WT_cs1_1 = wT + 196608;   // [512][256]
    const short* WT_c0W2  = wT + 327680;   // [256][512]
    const short* WT_cs2_0 = wT + 458752;   // [256][512]
    const short* WT_cs2_1 = wT + 589824;   // [256][512]

    dim3 blk(256);
    const int eb = (NEDGES + 255) / 256;
    dim3 g1(512 / BN, MPAD / BM);   // Nn=512
    dim3 g2(256 / BN, MPAD / BM);   // Nn=256

    // ---- weight prep + CSR build
    k_prep<<<(720896 + 255) / 256, blk, 0, stream>>>(c0_W1, cs_W1, c0_W2, cs_W2, wT);
    hipMemsetAsync(cnt, 0, NNODES * sizeof(int), stream);
    k_hist<<<eb, blk, 0, stream>>>(e_dst, cnt);
    k_scan<<<1, 1024, 0, stream>>>(cnt, off);
    k_fill<<<eb, blk, 0, stream>>>(e_dst, e_src, edge_imp, off, srcs, ews);

    // ---- layer 0 (d=128)
    k_agg0<<<(NNODES * 32 + 255) / 256, blk, 0, stream>>>(srcs, ews, x, node_imp,
                                                          c0_eps, off, zB);
    k_gemm<true><<<g1, blk, 0, stream>>>(zB, WT_c0W1, c0_b1, c0_bn, tB, 128, 512);
    k_gemm<true><<<g2, blk, 0, stream>>>(tB, WT_c0W2, c0_b2, obn, hB, 512, 256);

    // ---- layers 1,2 (d=256)
    for (int i = 0; i < 2; ++i) {
        k_agg256<<<(NNODES * 32 + 255) / 256, blk, 0, stream>>>(srcs, ews, hB,
                                                                cs_eps + i, off, zB);
        const short* W1 = (i == 0) ? WT_cs1_0 : WT_cs1_1;
        const short* W2 = (i == 0) ? WT_cs2_0 : WT_cs2_1;
        const float* b1 = cs_b1 + (size_t)i * 512;
        const float* bn1 = cs_bn + (size_t)i * 4 * 512;
        const float* b2 = cs_b2 + (size_t)i * 256;
        const float* ob = obn + (size_t)(i + 1) * 4 * 256;
        k_gemm<true><<<g1, blk, 0, stream>>>(zB, W1, b1, bn1, tB, 256, 512);
        if (i == 0)
            k_gemm<true><<<g2, blk, 0, stream>>>(tB, W2, b2, ob, hB, 512, 256);
        else
            k_gemm<false><<<g2, blk, 0, stream>>>(tB, W2, b2, ob, hB, 512, 256);
    }

    // ---- attention + edge keys (off in d_out is dead now)
    k_att<<<(NNODES * 64 + 255) / 256, blk, 0, stream>>>(hB, att_W, att_b, out);
    k_edge<<<eb, blk, 0, stream>>>(ei, out, out + NNODES);
}

// Round 4
// 254.946 us; speedup vs baseline: 12.7343x; 1.0451x over previous
//
#include <hip/hip_runtime.h>
#include <math.h>

#define NNODES 20000
#define NEDGES 320000
#define MPAD   20096          // 157 * 128
#define BM 128
#define BK 64
#define SCB 79                // ceil(NNODES/256)

typedef __attribute__((ext_vector_type(8))) short bf16x8;
typedef __attribute__((ext_vector_type(4))) float f32x4;

__device__ __forceinline__ short f2bf(float f) {
    unsigned u = __builtin_bit_cast(unsigned, f);
    u += 0x7fff + ((u >> 16) & 1);
    return (short)(u >> 16);
}
__device__ __forceinline__ float bf2f(unsigned short u) {
    return __builtin_bit_cast(float, (unsigned)u << 16);
}
__device__ __forceinline__ void gload16(const void* g, void* l) {
    __builtin_amdgcn_global_load_lds((const __attribute__((address_space(1))) void*)g,
                                     (__attribute__((address_space(3))) void*)l, 16, 0, 0);
}

// ================================================================ CSR build
__global__ __launch_bounds__(256) void k_hist(const int* __restrict__ dst,
                                              int* __restrict__ cnt) {
    int e = blockIdx.x * 256 + threadIdx.x;
    if (e >= NEDGES) return;
    atomicAdd(&cnt[dst[e]], 1);
}

// block-level inclusive scan; off gets exclusive-within-block, bsum gets block total
__global__ __launch_bounds__(256) void k_scan1(const int* __restrict__ cnt,
                                               int* __restrict__ off,
                                               int* __restrict__ bsum) {
    __shared__ int sm[256];
    const int t = threadIdx.x;
    const int i = blockIdx.x * 256 + t;
    int c = (i < NNODES) ? cnt[i] : 0;
    int v = c;
    sm[t] = v;
    __syncthreads();
    #pragma unroll
    for (int d = 1; d < 256; d <<= 1) {
        int u = (t >= d) ? sm[t - d] : 0;
        __syncthreads();
        v += u;
        sm[t] = v;
        __syncthreads();
    }
    if (i < NNODES) off[i] = v - c;           // exclusive start
    if (t == 255) bsum[blockIdx.x] = v;
}

// add exclusive prefix of bsum[0..b-1] to this block's off entries
__global__ __launch_bounds__(256) void k_scan2(const int* __restrict__ bsum,
                                               int* __restrict__ off) {
    __shared__ int sm[256];
    const int b = blockIdx.x, t = threadIdx.x;
    sm[t] = (t < b) ? bsum[t] : 0;            // b <= 78 < 79 entries
    __syncthreads();
    #pragma unroll
    for (int d = 128; d > 0; d >>= 1) {
        if (t < d) sm[t] += sm[t + d];
        __syncthreads();
    }
    int pre = sm[0];
    int i = b * 256 + t;
    if (i < NNODES) off[i] += pre;
}

// fill CSR-ordered src ids and edge weights; off[i] becomes end-of-node-i
__global__ __launch_bounds__(256) void k_fill(const int* __restrict__ dst,
                                              const int* __restrict__ src,
                                              const float* __restrict__ ew,
                                              int* __restrict__ off,
                                              int* __restrict__ srcs,
                                              float* __restrict__ ews) {
    int e = blockIdx.x * 256 + threadIdx.x;
    if (e >= NEDGES) return;
    int p = atomicAdd(&off[dst[e]], 1);
    srcs[p] = src[e];
    ews[p] = ew[e];
}

// ================================================================ weight prep: fp32 [K][N] -> bf16 [N][K]
__global__ __launch_bounds__(256) void k_prep(const float* __restrict__ c0W1,
                                              const float* __restrict__ csW1,
                                              const float* __restrict__ c0W2,
                                              const float* __restrict__ csW2,
                                              short* __restrict__ wT) {
    int i = blockIdx.x * 256 + threadIdx.x;
    if (i >= 720896) return;
    const float* src; int K, N2, base;
    if (i < 65536)       { src = c0W1;          base = 0;      K = 128; N2 = 512; }
    else if (i < 196608) { src = csW1;          base = 65536;  K = 256; N2 = 512; }
    else if (i < 327680) { src = csW1 + 131072; base = 196608; K = 256; N2 = 512; }
    else if (i < 458752) { src = c0W2;          base = 327680; K = 512; N2 = 256; }
    else if (i < 589824) { src = csW2;          base = 458752; K = 512; N2 = 256; }
    else                 { src = csW2 + 131072; base = 589824; K = 512; N2 = 256; }
    int j = i - base;
    int n = j / K, k = j - n * K;
    wT[i] = f2bf(src[(size_t)k * N2 + n]);
}

// ================================================================ xb = bf16(x * node_imp)
__global__ __launch_bounds__(256) void k_xprep(const float* __restrict__ x,
                                               const float* __restrict__ ni,
                                               short* __restrict__ xb) {
    int i = blockIdx.x * 256 + threadIdx.x;       // one per 8 channels
    if (i >= NNODES * 16) return;
    float s = ni[i >> 4];
    float4 a = reinterpret_cast<const float4*>(x)[i * 2];
    float4 b = reinterpret_cast<const float4*>(x)[i * 2 + 1];
    ushort e[8];
    e[0] = (ushort)f2bf(a.x * s); e[1] = (ushort)f2bf(a.y * s);
    e[2] = (ushort)f2bf(a.z * s); e[3] = (ushort)f2bf(a.w * s);
    e[4] = (ushort)f2bf(b.x * s); e[5] = (ushort)f2bf(b.y * s);
    e[6] = (ushort)f2bf(b.z * s); e[7] = (ushort)f2bf(b.w * s);
    uint4 o;
    o.x = e[0] | ((unsigned)e[1] << 16);
    o.y = e[2] | ((unsigned)e[3] << 16);
    o.z = e[4] | ((unsigned)e[5] << 16);
    o.w = e[6] | ((unsigned)e[7] << 16);
    reinterpret_cast<uint4*>(xb)[i] = o;
}

// ================================================================ aggregation (gather, bf16)
// layer 0: z[n] = (1+eps)*xb[n] + sum relu(xb[s]*ew); D=128, 32 lanes x 4 ch (8B)
__global__ __launch_bounds__(256) void k_agg0(const int* __restrict__ srcs,
                                              const float* __restrict__ ews,
                                              const short* __restrict__ xb,
                                              const float* __restrict__ epsp,
                                              const int* __restrict__ off,
                                              short* __restrict__ z) {
    int node = (blockIdx.x * 256 + threadIdx.x) >> 5;
    int lane = threadIdx.x & 31;
    if (node >= NNODES) return;
    const float eps1 = 1.0f + epsp[0];
    int p0 = (node == 0) ? 0 : off[node - 1];
    int p1 = off[node];
    uint2 hv = *reinterpret_cast<const uint2*>(xb + (size_t)node * 128 + lane * 4);
    float a0 = eps1 * __builtin_bit_cast(float, hv.x << 16);
    float a1 = eps1 * __builtin_bit_cast(float, hv.x & 0xffff0000u);
    float a2 = eps1 * __builtin_bit_cast(float, hv.y << 16);
    float a3 = eps1 * __builtin_bit_cast(float, hv.y & 0xffff0000u);
    for (int p = p0; p < p1; ++p) {
        int s = srcs[p];
        float w = ews[p];
        uint2 v = *reinterpret_cast<const uint2*>(xb + (size_t)s * 128 + lane * 4);
        a0 += fmaxf(__builtin_bit_cast(float, v.x << 16) * w, 0.f);
        a1 += fmaxf(__builtin_bit_cast(float, v.x & 0xffff0000u) * w, 0.f);
        a2 += fmaxf(__builtin_bit_cast(float, v.y << 16) * w, 0.f);
        a3 += fmaxf(__builtin_bit_cast(float, v.y & 0xffff0000u) * w, 0.f);
    }
    short4 o;
    o.x = f2bf(a0); o.y = f2bf(a1); o.z = f2bf(a2); o.w = f2bf(a3);
    *reinterpret_cast<short4*>(z + (size_t)node * 128 + lane * 4) = o;
}

// layers 1,2: D=256 bf16, 32 lanes x 8 ch
__global__ __launch_bounds__(256) void k_agg256(const int* __restrict__ srcs,
                                                const float* __restrict__ ews,
                                                const short* __restrict__ h,
                                                const float* __restrict__ epsp,
                                                const int* __restrict__ off,
                                                short* __restrict__ z) {
    int node = (blockIdx.x * 256 + threadIdx.x) >> 5;
    int lane = threadIdx.x & 31;
    if (node >= NNODES) return;
    const float eps1 = 1.0f + epsp[0];
    int p0 = (node == 0) ? 0 : off[node - 1];
    int p1 = off[node];
    uint4 hv = *reinterpret_cast<const uint4*>(h + (size_t)node * 256 + lane * 8);
    float acc[8];
    acc[0] = eps1 * __builtin_bit_cast(float, hv.x << 16);
    acc[1] = eps1 * __builtin_bit_cast(float, hv.x & 0xffff0000u);
    acc[2] = eps1 * __builtin_bit_cast(float, hv.y << 16);
    acc[3] = eps1 * __builtin_bit_cast(float, hv.y & 0xffff0000u);
    acc[4] = eps1 * __builtin_bit_cast(float, hv.z << 16);
    acc[5] = eps1 * __builtin_bit_cast(float, hv.z & 0xffff0000u);
    acc[6] = eps1 * __builtin_bit_cast(float, hv.w << 16);
    acc[7] = eps1 * __builtin_bit_cast(float, hv.w & 0xffff0000u);
    for (int p = p0; p < p1; ++p) {
        int s = srcs[p];
        float w = ews[p];
        uint4 v = *reinterpret_cast<const uint4*>(h + (size_t)s * 256 + lane * 8);
        acc[0] += fmaxf(__builtin_bit_cast(float, v.x << 16) * w, 0.f);
        acc[1] += fmaxf(__builtin_bit_cast(float, v.x & 0xffff0000u) * w, 0.f);
        acc[2] += fmaxf(__builtin_bit_cast(float, v.y << 16) * w, 0.f);
        acc[3] += fmaxf(__builtin_bit_cast(float, v.y & 0xffff0000u) * w, 0.f);
        acc[4] += fmaxf(__builtin_bit_cast(float, v.z << 16) * w, 0.f);
        acc[5] += fmaxf(__builtin_bit_cast(float, v.z & 0xffff0000u) * w, 0.f);
        acc[6] += fmaxf(__builtin_bit_cast(float, v.w << 16) * w, 0.f);
        acc[7] += fmaxf(__builtin_bit_cast(float, v.w & 0xffff0000u) * w, 0.f);
    }
    ushort oe[8];
    #pragma unroll
    for (int j = 0; j < 8; ++j) oe[j] = (ushort)f2bf(acc[j]);
    uint4 ov;
    ov.x = oe[0] | ((unsigned)oe[1] << 16);
    ov.y = oe[2] | ((unsigned)oe[3] << 16);
    ov.z = oe[4] | ((unsigned)oe[5] << 16);
    ov.w = oe[6] | ((unsigned)oe[7] << 16);
    *reinterpret_cast<uint4*>(z + (size_t)node * 256 + lane * 8) = ov;
}

// ================================================================ bf16 MFMA GEMM
// C[MPAD][Nn] = post( A[MPAD][K] @ BT[Nn][K]^T + bias ), BN epilogue, opt ReLU
// tile BM x TBN; 4 waves as 2x2, wave tile 64 x (TBN/2)
template<int TBN, bool RELU>
__global__ __launch_bounds__(256) void k_gemm(
    const short* __restrict__ A,
    const short* __restrict__ BT,
    const float* __restrict__ bias,
    const float* __restrict__ bnp,   // [4][Nn]
    short* __restrict__ C, int K, int Nn)
{
    constexpr int NF = TBN / 32;               // B n-frags per wave
    __shared__ __align__(16) short As[BM * BK];
    __shared__ __align__(16) short Bs[TBN * BK];
    const int tid = threadIdx.x;
    const int lane = tid & 63;
    const int wid = tid >> 6;
    const int wr = wid >> 1, wc = wid & 1;
    const int row0 = blockIdx.y * BM;
    const int col0 = blockIdx.x * TBN;
    const int srow = tid >> 3;                 // 0..31 staging row
    const int schunk = tid & 7;                // 16B chunk slot

    f32x4 acc[4][NF];
    #pragma unroll
    for (int m = 0; m < 4; ++m)
        #pragma unroll
        for (int n = 0; n < NF; ++n)
            acc[m][n] = (f32x4){0.f, 0.f, 0.f, 0.f};

    for (int kt = 0; kt < K; kt += BK) {
        #pragma unroll
        for (int s = 0; s < 4; ++s) {
            int r = s * 32 + srow;
            int sc = schunk ^ (r & 7);         // pre-swizzled global source chunk
            gload16(A + (size_t)(row0 + r) * K + kt + sc * 8,
                    (char*)As + s * 4096 + tid * 16);
        }
        #pragma unroll
        for (int s = 0; s < TBN / 32; ++s) {
            int r = s * 32 + srow;
            int sc = schunk ^ (r & 7);
            gload16(BT + (size_t)(col0 + r) * K + kt + sc * 8,
                    (char*)Bs + s * 4096 + tid * 16);
        }
        __syncthreads();
        #pragma unroll
        for (int ks = 0; ks < 2; ++ks) {
            bf16x8 af[4], bfr[NF];
            #pragma unroll
            for (int m = 0; m < 4; ++m) {
                int r = wr * 64 + m * 16 + (lane & 15);
                int c = (ks * 4 + (lane >> 4)) ^ (r & 7);
                af[m] = *(const bf16x8*)((const char*)As + r * 128 + c * 16);
            }
            #pragma unroll
            for (int n = 0; n < NF; ++n) {
                int r = wc * (TBN / 2) + n * 16 + (lane & 15);
                int c = (ks * 4 + (lane >> 4)) ^ (r & 7);
                bfr[n] = *(const bf16x8*)((const char*)Bs + r * 128 + c * 16);
            }
            #pragma unroll
            for (int m = 0; m < 4; ++m)
                #pragma unroll
                for (int n = 0; n < NF; ++n)
                    acc[m][n] = __builtin_amdgcn_mfma_f32_16x16x32_bf16(af[m], bfr[n], acc[m][n], 0, 0, 0);
        }
        __syncthreads();
    }

    const int cb = col0 + wc * (TBN / 2) + (lane & 15);
    float scl[NF], shf[NF];
    #pragma unroll
    for (int n = 0; n < NF; ++n) {
        int c = cb + n * 16;
        float ga = bnp[c], be = bnp[Nn + c], mu = bnp[2 * Nn + c], va = bnp[3 * Nn + c];
        float s = ga * rsqrtf(va + 1e-5f);
        scl[n] = s;
        shf[n] = be - mu * s + bias[c] * s;
    }
    const int rb = row0 + wr * 64 + 4 * (lane >> 4);
    #pragma unroll
    for (int m = 0; m < 4; ++m) {
        #pragma unroll
        for (int j = 0; j < 4; ++j) {
            int r = rb + m * 16 + j;
            #pragma unroll
            for (int n = 0; n < NF; ++n) {
                float o = acc[m][n][j] * scl[n] + shf[n];
                if (RELU) o = fmaxf(o, 0.f);
                C[(size_t)r * Nn + cb + n * 16] = f2bf(o);
            }
        }
    }
}

// ================================================================ attention + edges
__global__ __launch_bounds__(256) void k_att(const short* __restrict__ h,
                                             const float* __restrict__ attW,
                                             const float* __restrict__ attb,
                                             float* __restrict__ nk) {
    int wid = (blockIdx.x * 256 + threadIdx.x) >> 6;
    int lane = threadIdx.x & 63;
    if (wid >= NNODES) return;
    ushort4 v = *reinterpret_cast<const ushort4*>(h + (size_t)wid * 256 + lane * 4);
    float4 w = reinterpret_cast<const float4*>(attW)[lane];
    float s = bf2f(v.x) * w.x + bf2f(v.y) * w.y + bf2f(v.z) * w.z + bf2f(v.w) * w.w;
    #pragma unroll
    for (int o = 32; o > 0; o >>= 1) s += __shfl_xor(s, o);
    if (lane == 0) {
        s += attb[0];
        nk[wid] = 1.f / (1.f + expf(-s));
    }
}

__global__ __launch_bounds__(256) void k_edge(const int* __restrict__ ei,
                                              const float* __restrict__ nk,
                                              float* __restrict__ ek) {
    int e = blockIdx.x * 256 + threadIdx.x;
    if (e >= NEDGES) return;
    ek[e] = nk[ei[e]] * nk[ei[NEDGES + e]];
}

// ================================================================
extern "C" void kernel_launch(void* const* d_in, const int* in_sizes, int n_in,
                              void* d_out, int out_size, void* d_ws, size_t ws_size,
                              hipStream_t stream) {
    const float* x        = (const float*)d_in[0];
    const int*   ei       = (const int*)d_in[1];
    const float* node_imp = (const float*)d_in[2];
    const float* edge_imp = (const float*)d_in[3];
    const float* c0_W1    = (const float*)d_in[4];
    const float* c0_b1    = (const float*)d_in[5];
    const float* c0_bn    = (const float*)d_in[6];
    const float* c0_W2    = (const float*)d_in[7];
    const float* c0_b2    = (const float*)d_in[8];
    const float* c0_eps   = (const float*)d_in[9];
    const float* cs_W1    = (const float*)d_in[10];
    const float* cs_b1    = (const float*)d_in[11];
    const float* cs_bn    = (const float*)d_in[12];
    const float* cs_W2    = (const float*)d_in[13];
    const float* cs_b2    = (const float*)d_in[14];
    const float* cs_eps   = (const float*)d_in[15];
    const float* obn      = (const float*)d_in[16];
    const float* att_W    = (const float*)d_in[17];
    const float* att_b    = (const float*)d_in[18];
    float* out = (float*)d_out;

    const int* e_src = ei;
    const int* e_dst = ei + NEDGES;

    // workspace layout
    short* zB = (short*)d_ws;                   // [MPAD][256] (layer0 uses 128)
    short* tB = zB + (size_t)MPAD * 256;        // [MPAD][512]
    short* hB = tB + (size_t)MPAD * 512;        // [MPAD][256]
    short* wT = hB + (size_t)MPAD * 256;        // 720896 bf16
    short* xb = wT + 720896;                    // [NNODES][128] bf16
    int*   srcs = (int*)(xb + (size_t)NNODES * 128);   // E
    float* ews  = (float*)(srcs + NEDGES);      // E
    int*   cnt  = (int*)(ews + NEDGES);         // N
    int*   bsum = cnt + NNODES;                 // SCB
    int*   off  = (int*)d_out;                  // N (dead before k_att writes)

    const short* WT_c0W1  = wT + 0;        // [512][128]
    const short* WT_cs1_0 = wT + 65536;    // [512][256]
    const short* WT_cs1_1 = wT + 196608;   // [512][256]
    const short* WT_c0W2  = wT + 327680;   // [256][512]
    const short* WT_cs2_0 = wT + 458752;   // [256][512]
    const short* WT_cs2_1 = wT + 589824;   // [256][512]

    dim3 blk(256);
    const int eb = (NEDGES + 255) / 256;
    dim3 g1(512 / 128, MPAD / BM);   // GEMM1: TBN=128
    dim3 g2(256 / 64,  MPAD / BM);   // GEMM2: TBN=64 -> 628 blocks

    // ---- weight prep + CSR build
    k_prep<<<(720896 + 255) / 256, blk, 0, stream>>>(c0_W1, cs_W1, c0_W2, cs_W2, wT);
    k_xprep<<<(NNODES * 16 + 255) / 256, blk, 0, stream>>>(x, node_imp, xb);
    hipMemsetAsync(cnt, 0, NNODES * sizeof(int), stream);
    k_hist<<<eb, blk, 0, stream>>>(e_dst, cnt);
    k_scan1<<<SCB, blk, 0, stream>>>(cnt, off, bsum);
    k_scan2<<<SCB, blk, 0, stream>>>(bsum, off);
    k_fill<<<eb, blk, 0, stream>>>(e_dst, e_src, edge_imp, off, srcs, ews);

    // ---- layer 0 (d=128)
    k_agg0<<<(NNODES * 32 + 255) / 256, blk, 0, stream>>>(srcs, ews, xb, c0_eps, off, zB);
    k_gemm<128, true><<<g1, blk, 0, stream>>>(zB, WT_c0W1, c0_b1, c0_bn, tB, 128, 512);
    k_gemm<64, true><<<g2, blk, 0, stream>>>(tB, WT_c0W2, c0_b2, obn, hB, 512, 256);

    // ---- layers 1,2 (d=256)
    for (int i = 0; i < 2; ++i) {
        k_agg256<<<(NNODES * 32 + 255) / 256, blk, 0, stream>>>(srcs, ews, hB,
                                                                cs_eps + i, off, zB);
        const short* W1 = (i == 0) ? WT_cs1_0 : WT_cs1_1;
        const short* W2 = (i == 0) ? WT_cs2_0 : WT_cs2_1;
        const float* b1 = cs_b1 + (size_t)i * 512;
        const float* bn1 = cs_bn + (size_t)i * 4 * 512;
        const float* b2 = cs_b2 + (size_t)i * 256;
        const float* ob = obn + (size_t)(i + 1) * 4 * 256;
        k_gemm<128, true><<<g1, blk, 0, stream>>>(zB, W1, b1, bn1, tB, 256, 512);
        if (i == 0)
            k_gemm<64, true><<<g2, blk, 0, stream>>>(tB, W2, b2, ob, hB, 512, 256);
        else
            k_gemm<64, false><<<g2, blk, 0, stream>>>(tB, W2, b2, ob, hB, 512, 256);
    }

    // ---- attention + edge keys (off in d_out is dead now)
    k_att<<<(NNODES * 64 + 255) / 256, blk, 0, stream>>>(hB, att_W, att_b, out);
    k_edge<<<eb, blk, 0, stream>>>(ei, out, out + NNODES);
}

// Round 5
// 242.735 us; speedup vs baseline: 13.3749x; 1.0503x over previous
//
#include <hip/hip_runtime.h>
#include <math.h>

#define NNODES 20000
#define NEDGES 320000
#define MPAD   20096          // 157 * 128
#define BM 128
#define BK 64
#define SCB 79                // ceil(NNODES/256)

typedef __attribute__((ext_vector_type(8))) short bf16x8;
typedef __attribute__((ext_vector_type(4))) float f32x4;

__device__ __forceinline__ short f2bf(float f) {
    unsigned u = __builtin_bit_cast(unsigned, f);
    u += 0x7fff + ((u >> 16) & 1);
    return (short)(u >> 16);
}
__device__ __forceinline__ float bf2f(unsigned short u) {
    return __builtin_bit_cast(float, (unsigned)u << 16);
}
__device__ __forceinline__ void gload16(const void* g, void* l) {
    __builtin_amdgcn_global_load_lds((const __attribute__((address_space(1))) void*)g,
                                     (__attribute__((address_space(3))) void*)l, 16, 0, 0);
}

// ================================================================ fused prep:
// [0, 720896)              : weight transpose fp32 [K][N] -> bf16 [N][K]
// [720896, +320000)        : xb = bf16(x * node_imp)   (j = node*16 + chunk8)
// [+320000, +20000)        : cnt zero
__global__ __launch_bounds__(256) void k_prep(const float* __restrict__ c0W1,
                                              const float* __restrict__ csW1,
                                              const float* __restrict__ c0W2,
                                              const float* __restrict__ csW2,
                                              const float* __restrict__ x,
                                              const float* __restrict__ ni,
                                              short* __restrict__ wT,
                                              short* __restrict__ xb,
                                              int* __restrict__ cnt) {
    int i = blockIdx.x * 256 + threadIdx.x;
    if (i < 720896) {
        const float* src; int K, N2, base;
        if (i < 65536)       { src = c0W1;          base = 0;      K = 128; N2 = 512; }
        else if (i < 196608) { src = csW1;          base = 65536;  K = 256; N2 = 512; }
        else if (i < 327680) { src = csW1 + 131072; base = 196608; K = 256; N2 = 512; }
        else if (i < 458752) { src = c0W2;          base = 327680; K = 512; N2 = 256; }
        else if (i < 589824) { src = csW2;          base = 458752; K = 512; N2 = 256; }
        else                 { src = csW2 + 131072; base = 589824; K = 512; N2 = 256; }
        int j = i - base;
        int n = j / K, k = j - n * K;
        wT[i] = f2bf(src[(size_t)k * N2 + n]);
        return;
    }
    int j = i - 720896;
    if (j < NNODES * 16) {
        float s = ni[j >> 4];
        float4 a = reinterpret_cast<const float4*>(x)[j * 2];
        float4 b = reinterpret_cast<const float4*>(x)[j * 2 + 1];
        ushort e[8];
        e[0] = (ushort)f2bf(a.x * s); e[1] = (ushort)f2bf(a.y * s);
        e[2] = (ushort)f2bf(a.z * s); e[3] = (ushort)f2bf(a.w * s);
        e[4] = (ushort)f2bf(b.x * s); e[5] = (ushort)f2bf(b.y * s);
        e[6] = (ushort)f2bf(b.z * s); e[7] = (ushort)f2bf(b.w * s);
        uint4 o;
        o.x = e[0] | ((unsigned)e[1] << 16);
        o.y = e[2] | ((unsigned)e[3] << 16);
        o.z = e[4] | ((unsigned)e[5] << 16);
        o.w = e[6] | ((unsigned)e[7] << 16);
        reinterpret_cast<uint4*>(xb)[j] = o;
        return;
    }
    int k = j - NNODES * 16;
    if (k < NNODES) cnt[k] = 0;
}

// ================================================================ CSR build
__global__ __launch_bounds__(256) void k_hist(const int* __restrict__ dst,
                                              int* __restrict__ cnt) {
    int e = blockIdx.x * 256 + threadIdx.x;
    if (e >= NEDGES) return;
    atomicAdd(&cnt[dst[e]], 1);
}

__global__ __launch_bounds__(256) void k_scan1(const int* __restrict__ cnt,
                                               int* __restrict__ off,
                                               int* __restrict__ bsum) {
    __shared__ int sm[256];
    const int t = threadIdx.x;
    const int i = blockIdx.x * 256 + t;
    int c = (i < NNODES) ? cnt[i] : 0;
    int v = c;
    sm[t] = v;
    __syncthreads();
    #pragma unroll
    for (int d = 1; d < 256; d <<= 1) {
        int u = (t >= d) ? sm[t - d] : 0;
        __syncthreads();
        v += u;
        sm[t] = v;
        __syncthreads();
    }
    if (i < NNODES) off[i] = v - c;
    if (t == 255) bsum[blockIdx.x] = v;
}

__global__ __launch_bounds__(256) void k_scan2(const int* __restrict__ bsum,
                                               int* __restrict__ off) {
    __shared__ int sm[256];
    const int b = blockIdx.x, t = threadIdx.x;
    sm[t] = (t < b) ? bsum[t] : 0;
    __syncthreads();
    #pragma unroll
    for (int d = 128; d > 0; d >>= 1) {
        if (t < d) sm[t] += sm[t + d];
        __syncthreads();
    }
    int pre = sm[0];
    int i = b * 256 + t;
    if (i < NNODES) off[i] += pre;
}

// fill CSR-ordered (src, ew) pairs; off[i] becomes end-of-node-i
__global__ __launch_bounds__(256) void k_fill(const int* __restrict__ dst,
                                              const int* __restrict__ src,
                                              const float* __restrict__ ew,
                                              int* __restrict__ off,
                                              int2* __restrict__ edg) {
    int e = blockIdx.x * 256 + threadIdx.x;
    if (e >= NEDGES) return;
    int p = atomicAdd(&off[dst[e]], 1);
    edg[p] = make_int2(src[e], __builtin_bit_cast(int, ew[e]));
}

// ================================================================ aggregation (gather, bf16)
// layer 0: D=128, 32 lanes x 4 ch (8B/lane), unroll x2
__global__ __launch_bounds__(256) void k_agg0(const int2* __restrict__ edg,
                                              const short* __restrict__ xb,
                                              const float* __restrict__ epsp,
                                              const int* __restrict__ off,
                                              short* __restrict__ z) {
    int node = (blockIdx.x * 256 + threadIdx.x) >> 5;
    int lane = threadIdx.x & 31;
    if (node >= NNODES) return;
    const float eps1 = 1.0f + epsp[0];
    int p0 = (node == 0) ? 0 : off[node - 1];
    int p1 = off[node];
    uint2 hv = *reinterpret_cast<const uint2*>(xb + (size_t)node * 128 + lane * 4);
    float a0 = eps1 * __builtin_bit_cast(float, hv.x << 16);
    float a1 = eps1 * __builtin_bit_cast(float, hv.x & 0xffff0000u);
    float a2 = eps1 * __builtin_bit_cast(float, hv.y << 16);
    float a3 = eps1 * __builtin_bit_cast(float, hv.y & 0xffff0000u);
    float b0 = 0.f, b1 = 0.f, b2 = 0.f, b3 = 0.f;
    int p = p0;
    for (; p + 1 < p1; p += 2) {
        int2 q0 = edg[p], q1 = edg[p + 1];
        float w0 = __builtin_bit_cast(float, q0.y);
        float w1 = __builtin_bit_cast(float, q1.y);
        uint2 v0 = *reinterpret_cast<const uint2*>(xb + (size_t)q0.x * 128 + lane * 4);
        uint2 v1 = *reinterpret_cast<const uint2*>(xb + (size_t)q1.x * 128 + lane * 4);
        a0 += fmaxf(__builtin_bit_cast(float, v0.x << 16) * w0, 0.f);
        a1 += fmaxf(__builtin_bit_cast(float, v0.x & 0xffff0000u) * w0, 0.f);
        a2 += fmaxf(__builtin_bit_cast(float, v0.y << 16) * w0, 0.f);
        a3 += fmaxf(__builtin_bit_cast(float, v0.y & 0xffff0000u) * w0, 0.f);
        b0 += fmaxf(__builtin_bit_cast(float, v1.x << 16) * w1, 0.f);
        b1 += fmaxf(__builtin_bit_cast(float, v1.x & 0xffff0000u) * w1, 0.f);
        b2 += fmaxf(__builtin_bit_cast(float, v1.y << 16) * w1, 0.f);
        b3 += fmaxf(__builtin_bit_cast(float, v1.y & 0xffff0000u) * w1, 0.f);
    }
    if (p < p1) {
        int2 q0 = edg[p];
        float w0 = __builtin_bit_cast(float, q0.y);
        uint2 v0 = *reinterpret_cast<const uint2*>(xb + (size_t)q0.x * 128 + lane * 4);
        a0 += fmaxf(__builtin_bit_cast(float, v0.x << 16) * w0, 0.f);
        a1 += fmaxf(__builtin_bit_cast(float, v0.x & 0xffff0000u) * w0, 0.f);
        a2 += fmaxf(__builtin_bit_cast(float, v0.y << 16) * w0, 0.f);
        a3 += fmaxf(__builtin_bit_cast(float, v0.y & 0xffff0000u) * w0, 0.f);
    }
    short4 o;
    o.x = f2bf(a0 + b0); o.y = f2bf(a1 + b1); o.z = f2bf(a2 + b2); o.w = f2bf(a3 + b3);
    *reinterpret_cast<short4*>(z + (size_t)node * 128 + lane * 4) = o;
}

// layers 1,2: D=256, 32 lanes x 8 ch (16B/lane), unroll x2
__global__ __launch_bounds__(256) void k_agg256(const int2* __restrict__ edg,
                                                const short* __restrict__ h,
                                                const float* __restrict__ epsp,
                                                const int* __restrict__ off,
                                                short* __restrict__ z) {
    int node = (blockIdx.x * 256 + threadIdx.x) >> 5;
    int lane = threadIdx.x & 31;
    if (node >= NNODES) return;
    const float eps1 = 1.0f + epsp[0];
    int p0 = (node == 0) ? 0 : off[node - 1];
    int p1 = off[node];
    uint4 hv = *reinterpret_cast<const uint4*>(h + (size_t)node * 256 + lane * 8);
    float acc[8], acc2[8];
    acc[0] = eps1 * __builtin_bit_cast(float, hv.x << 16);
    acc[1] = eps1 * __builtin_bit_cast(float, hv.x & 0xffff0000u);
    acc[2] = eps1 * __builtin_bit_cast(float, hv.y << 16);
    acc[3] = eps1 * __builtin_bit_cast(float, hv.y & 0xffff0000u);
    acc[4] = eps1 * __builtin_bit_cast(float, hv.z << 16);
    acc[5] = eps1 * __builtin_bit_cast(float, hv.z & 0xffff0000u);
    acc[6] = eps1 * __builtin_bit_cast(float, hv.w << 16);
    acc[7] = eps1 * __builtin_bit_cast(float, hv.w & 0xffff0000u);
    #pragma unroll
    for (int j = 0; j < 8; ++j) acc2[j] = 0.f;
    int p = p0;
    for (; p + 1 < p1; p += 2) {
        int2 q0 = edg[p], q1 = edg[p + 1];
        float w0 = __builtin_bit_cast(float, q0.y);
        float w1 = __builtin_bit_cast(float, q1.y);
        uint4 v0 = *reinterpret_cast<const uint4*>(h + (size_t)q0.x * 256 + lane * 8);
        uint4 v1 = *reinterpret_cast<const uint4*>(h + (size_t)q1.x * 256 + lane * 8);
        acc[0] += fmaxf(__builtin_bit_cast(float, v0.x << 16) * w0, 0.f);
        acc[1] += fmaxf(__builtin_bit_cast(float, v0.x & 0xffff0000u) * w0, 0.f);
        acc[2] += fmaxf(__builtin_bit_cast(float, v0.y << 16) * w0, 0.f);
        acc[3] += fmaxf(__builtin_bit_cast(float, v0.y & 0xffff0000u) * w0, 0.f);
        acc[4] += fmaxf(__builtin_bit_cast(float, v0.z << 16) * w0, 0.f);
        acc[5] += fmaxf(__builtin_bit_cast(float, v0.z & 0xffff0000u) * w0, 0.f);
        acc[6] += fmaxf(__builtin_bit_cast(float, v0.w << 16) * w0, 0.f);
        acc[7] += fmaxf(__builtin_bit_cast(float, v0.w & 0xffff0000u) * w0, 0.f);
        acc2[0] += fmaxf(__builtin_bit_cast(float, v1.x << 16) * w1, 0.f);
        acc2[1] += fmaxf(__builtin_bit_cast(float, v1.x & 0xffff0000u) * w1, 0.f);
        acc2[2] += fmaxf(__builtin_bit_cast(float, v1.y << 16) * w1, 0.f);
        acc2[3] += fmaxf(__builtin_bit_cast(float, v1.y & 0xffff0000u) * w1, 0.f);
        acc2[4] += fmaxf(__builtin_bit_cast(float, v1.z << 16) * w1, 0.f);
        acc2[5] += fmaxf(__builtin_bit_cast(float, v1.z & 0xffff0000u) * w1, 0.f);
        acc2[6] += fmaxf(__builtin_bit_cast(float, v1.w << 16) * w1, 0.f);
        acc2[7] += fmaxf(__builtin_bit_cast(float, v1.w & 0xffff0000u) * w1, 0.f);
    }
    if (p < p1) {
        int2 q0 = edg[p];
        float w0 = __builtin_bit_cast(float, q0.y);
        uint4 v0 = *reinterpret_cast<const uint4*>(h + (size_t)q0.x * 256 + lane * 8);
        acc[0] += fmaxf(__builtin_bit_cast(float, v0.x << 16) * w0, 0.f);
        acc[1] += fmaxf(__builtin_bit_cast(float, v0.x & 0xffff0000u) * w0, 0.f);
        acc[2] += fmaxf(__builtin_bit_cast(float, v0.y << 16) * w0, 0.f);
        acc[3] += fmaxf(__builtin_bit_cast(float, v0.y & 0xffff0000u) * w0, 0.f);
        acc[4] += fmaxf(__builtin_bit_cast(float, v0.z << 16) * w0, 0.f);
        acc[5] += fmaxf(__builtin_bit_cast(float, v0.z & 0xffff0000u) * w0, 0.f);
        acc[6] += fmaxf(__builtin_bit_cast(float, v0.w << 16) * w0, 0.f);
        acc[7] += fmaxf(__builtin_bit_cast(float, v0.w & 0xffff0000u) * w0, 0.f);
    }
    ushort oe[8];
    #pragma unroll
    for (int j = 0; j < 8; ++j) oe[j] = (ushort)f2bf(acc[j] + acc2[j]);
    uint4 ov;
    ov.x = oe[0] | ((unsigned)oe[1] << 16);
    ov.y = oe[2] | ((unsigned)oe[3] << 16);
    ov.z = oe[4] | ((unsigned)oe[5] << 16);
    ov.w = oe[6] | ((unsigned)oe[7] << 16);
    *reinterpret_cast<uint4*>(z + (size_t)node * 256 + lane * 8) = ov;
}

// ================================================================ bf16 MFMA GEMM
// C[MPAD][Nn] = post( A[MPAD][K] @ BT[Nn][K]^T + bias ), BN epilogue, opt ReLU
// Swapped-operand MFMA: D fragment has 4 consecutive COLS per lane -> short4 C stores.
template<int TBN, bool RELU>
__global__ __launch_bounds__(256) void k_gemm(
    const short* __restrict__ A,
    const short* __restrict__ BT,
    const float* __restrict__ bias,
    const float* __restrict__ bnp,   // [4][Nn]
    short* __restrict__ C, int K, int Nn)
{
    constexpr int NF = TBN / 32;               // B n-frags per wave
    __shared__ __align__(16) short As[BM * BK];
    __shared__ __align__(16) short Bs[TBN * BK];
    const int tid = threadIdx.x;
    const int lane = tid & 63;
    const int wid = tid >> 6;
    const int wr = wid >> 1, wc = wid & 1;
    const int row0 = blockIdx.y * BM;
    const int col0 = blockIdx.x * TBN;
    const int srow = tid >> 3;
    const int schunk = tid & 7;

    f32x4 acc[4][NF];
    #pragma unroll
    for (int m = 0; m < 4; ++m)
        #pragma unroll
        for (int n = 0; n < NF; ++n)
            acc[m][n] = (f32x4){0.f, 0.f, 0.f, 0.f};

    for (int kt = 0; kt < K; kt += BK) {
        #pragma unroll
        for (int s = 0; s < 4; ++s) {
            int r = s * 32 + srow;
            int sc = schunk ^ (r & 7);
            gload16(A + (size_t)(row0 + r) * K + kt + sc * 8,
                    (char*)As + s * 4096 + tid * 16);
        }
        #pragma unroll
        for (int s = 0; s < TBN / 32; ++s) {
            int r = s * 32 + srow;
            int sc = schunk ^ (r & 7);
            gload16(BT + (size_t)(col0 + r) * K + kt + sc * 8,
                    (char*)Bs + s * 4096 + tid * 16);
        }
        __syncthreads();
        #pragma unroll
        for (int ks = 0; ks < 2; ++ks) {
            bf16x8 af[4], bfr[NF];
            #pragma unroll
            for (int m = 0; m < 4; ++m) {
                int r = wr * 64 + m * 16 + (lane & 15);
                int c = (ks * 4 + (lane >> 4)) ^ (r & 7);
                af[m] = *(const bf16x8*)((const char*)As + r * 128 + c * 16);
            }
            #pragma unroll
            for (int n = 0; n < NF; ++n) {
                int r = wc * (TBN / 2) + n * 16 + (lane & 15);
                int c = (ks * 4 + (lane >> 4)) ^ (r & 7);
                bfr[n] = *(const bf16x8*)((const char*)Bs + r * 128 + c * 16);
            }
            // swapped operands: D rows <- BT rows (C cols), D cols <- A rows (C rows)
            #pragma unroll
            for (int m = 0; m < 4; ++m)
                #pragma unroll
                for (int n = 0; n < NF; ++n)
                    acc[m][n] = __builtin_amdgcn_mfma_f32_16x16x32_bf16(bfr[n], af[m], acc[m][n], 0, 0, 0);
        }
        __syncthreads();
    }

    // lane holds: row r = row0 + wr*64 + m*16 + (lane&15)
    //             cols c = col0 + wc*(TBN/2) + n*16 + 4*(lane>>4) + j, j=0..3
    const int cb2 = col0 + wc * (TBN / 2) + 4 * (lane >> 4);
    float4 scl[NF], shf[NF];
    #pragma unroll
    for (int n = 0; n < NF; ++n) {
        int c = cb2 + n * 16;
        float4 ga = *reinterpret_cast<const float4*>(bnp + c);
        float4 be = *reinterpret_cast<const float4*>(bnp + Nn + c);
        float4 mu = *reinterpret_cast<const float4*>(bnp + 2 * Nn + c);
        float4 va = *reinterpret_cast<const float4*>(bnp + 3 * Nn + c);
        float4 bi = *reinterpret_cast<const float4*>(bias + c);
        float4 s;
        s.x = ga.x * rsqrtf(va.x + 1e-5f);
        s.y = ga.y * rsqrtf(va.y + 1e-5f);
        s.z = ga.z * rsqrtf(va.z + 1e-5f);
        s.w = ga.w * rsqrtf(va.w + 1e-5f);
        scl[n] = s;
        shf[n].x = be.x - mu.x * s.x + bi.x * s.x;
        shf[n].y = be.y - mu.y * s.y + bi.y * s.y;
        shf[n].z = be.z - mu.z * s.z + bi.z * s.z;
        shf[n].w = be.w - mu.w * s.w + bi.w * s.w;
    }
    const int rb2 = row0 + wr * 64 + (lane & 15);
    #pragma unroll
    for (int m = 0; m < 4; ++m) {
        int r = rb2 + m * 16;
        #pragma unroll
        for (int n = 0; n < NF; ++n) {
            float o0 = acc[m][n][0] * scl[n].x + shf[n].x;
            float o1 = acc[m][n][1] * scl[n].y + shf[n].y;
            float o2 = acc[m][n][2] * scl[n].z + shf[n].z;
            float o3 = acc[m][n][3] * scl[n].w + shf[n].w;
            if (RELU) {
                o0 = fmaxf(o0, 0.f); o1 = fmaxf(o1, 0.f);
                o2 = fmaxf(o2, 0.f); o3 = fmaxf(o3, 0.f);
            }
            short4 ov;
            ov.x = f2bf(o0); ov.y = f2bf(o1); ov.z = f2bf(o2); ov.w = f2bf(o3);
            *reinterpret_cast<short4*>(C + (size_t)r * Nn + cb2 + n * 16) = ov;
        }
    }
}

// ================================================================ attention + edges
__global__ __launch_bounds__(256) void k_att(const short* __restrict__ h,
                                             const float* __restrict__ attW,
                                             const float* __restrict__ attb,
                                             float* __restrict__ nk) {
    int wid = (blockIdx.x * 256 + threadIdx.x) >> 6;
    int lane = threadIdx.x & 63;
    if (wid >= NNODES) return;
    ushort4 v = *reinterpret_cast<const ushort4*>(h + (size_t)wid * 256 + lane * 4);
    float4 w = reinterpret_cast<const float4*>(attW)[lane];
    float s = bf2f(v.x) * w.x + bf2f(v.y) * w.y + bf2f(v.z) * w.z + bf2f(v.w) * w.w;
    #pragma unroll
    for (int o = 32; o > 0; o >>= 1) s += __shfl_xor(s, o);
    if (lane == 0) {
        s += attb[0];
        nk[wid] = 1.f / (1.f + expf(-s));
    }
}

__global__ __launch_bounds__(256) void k_edge(const int* __restrict__ ei,
                                              const float* __restrict__ nk,
                                              float* __restrict__ ek) {
    int e = blockIdx.x * 256 + threadIdx.x;
    if (e >= NEDGES) return;
    ek[e] = nk[ei[e]] * nk[ei[NEDGES + e]];
}

// ================================================================
extern "C" void kernel_launch(void* const* d_in, const int* in_sizes, int n_in,
                              void* d_out, int out_size, void* d_ws, size_t ws_size,
                              hipStream_t stream) {
    const float* x        = (const float*)d_in[0];
    const int*   ei       = (const int*)d_in[1];
    const float* node_imp = (const float*)d_in[2];
    const float* edge_imp = (const float*)d_in[3];
    const float* c0_W1    = (const float*)d_in[4];
    const float* c0_b1    = (const float*)d_in[5];
    const float* c0_bn    = (const float*)d_in[6];
    const float* c0_W2    = (const float*)d_in[7];
    const float* c0_b2    = (const float*)d_in[8];
    const float* c0_eps   = (const float*)d_in[9];
    const float* cs_W1    = (const float*)d_in[10];
    const float* cs_b1    = (const float*)d_in[11];
    const float* cs_bn    = (const float*)d_in[12];
    const float* cs_W2    = (const float*)d_in[13];
    const float* cs_b2    = (const float*)d_in[14];
    const float* cs_eps   = (const float*)d_in[15];
    const float* obn      = (const float*)d_in[16];
    const float* att_W    = (const float*)d_in[17];
    const float* att_b    = (const float*)d_in[18];
    float* out = (float*)d_out;

    const int* e_src = ei;
    const int* e_dst = ei + NEDGES;

    // workspace layout
    short* zB = (short*)d_ws;                   // [MPAD][256] (layer0 uses 128)
    short* tB = zB + (size_t)MPAD * 256;        // [MPAD][512]
    short* hB = tB + (size_t)MPAD * 512;        // [MPAD][256]
    short* wT = hB + (size_t)MPAD * 256;        // 720896 bf16
    short* xb = wT + 720896;                    // [NNODES][128] bf16
    int2*  edg  = (int2*)(xb + (size_t)NNODES * 128);  // E pairs (src, ew)
    int*   cnt  = (int*)(edg + NEDGES);         // N
    int*   bsum = cnt + NNODES;                 // SCB
    int*   off  = (int*)d_out;                  // N (dead before k_att writes)

    const short* WT_c0W1  = wT + 0;        // [512][128]
    const short* WT_cs1_0 = wT + 65536;    // [512][256]
    const short* WT_cs1_1 = wT + 196608;   // [512][256]
    const short* WT_c0W2  = wT + 327680;   // [256][512]
    const short* WT_cs2_0 = wT + 458752;   // [256][512]
    const short* WT_cs2_1 = wT + 589824;   // [256][512]

    dim3 blk(256);
    const int eb = (NEDGES + 255) / 256;
    dim3 g1(512 / 128, MPAD / BM);   // GEMM1: TBN=128
    dim3 g2(256 / 64,  MPAD / BM);   // GEMM2: TBN=64 -> 628 blocks

    // ---- fused prep (weights + xb + cnt zero) + CSR build
    const int prepN = 720896 + NNODES * 16 + NNODES;
    k_prep<<<(prepN + 255) / 256, blk, 0, stream>>>(c0_W1, cs_W1, c0_W2, cs_W2,
                                                    x, node_imp, wT, xb, cnt);
    k_hist<<<eb, blk, 0, stream>>>(e_dst, cnt);
    k_scan1<<<SCB, blk, 0, stream>>>(cnt, off, bsum);
    k_scan2<<<SCB, blk, 0, stream>>>(bsum, off);
    k_fill<<<eb, blk, 0, stream>>>(e_dst, e_src, edge_imp, off, edg);

    // ---- layer 0 (d=128)
    k_agg0<<<(NNODES * 32 + 255) / 256, blk, 0, stream>>>(edg, xb, c0_eps, off, zB);
    k_gemm<128, true><<<g1, blk, 0, stream>>>(zB, WT_c0W1, c0_b1, c0_bn, tB, 128, 512);
    k_gemm<64, true><<<g2, blk, 0, stream>>>(tB, WT_c0W2, c0_b2, obn, hB, 512, 256);

    // ---- layers 1,2 (d=256)
    for (int i = 0; i < 2; ++i) {
        k_agg256<<<(NNODES * 32 + 255) / 256, blk, 0, stream>>>(edg, hB, cs_eps + i, off, zB);
        const short* W1 = (i == 0) ? WT_cs1_0 : WT_cs1_1;
        const short* W2 = (i == 0) ? WT_cs2_0 : WT_cs2_1;
        const float* b1 = cs_b1 + (size_t)i * 512;
        const float* bn1 = cs_bn + (size_t)i * 4 * 512;
        const float* b2 = cs_b2 + (size_t)i * 256;
        const float* ob = obn + (size_t)(i + 1) * 4 * 256;
        k_gemm<128, true><<<g1, blk, 0, stream>>>(zB, W1, b1, bn1, tB, 256, 512);
        if (i == 0)
            k_gemm<64, true><<<g2, blk, 0, stream>>>(tB, W2, b2, ob, hB, 512, 256);
        else
            k_gemm<64, false><<<g2, blk, 0, stream>>>(tB, W2, b2, ob, hB, 512, 256);
    }

    // ---- attention + edge keys (off in d_out is dead now)
    k_att<<<(NNODES * 64 + 255) / 256, blk, 0, stream>>>(hB, att_W, att_b, out);
    k_edge<<<eb, blk, 0, stream>>>(ei, out, out + NNODES);
}